// Round 1
// baseline (1069.418 us; speedup 1.0000x reference)
//
#include <hip/hip_runtime.h>

#define T_     24
#define LAMDA_ 0.2f

// output layout (flat f32): outs[24,64,256] | cs[64,256] | las[24,64,32] | gas[24,64,256]
#define OFF_CS  393216
#define OFF_LAS 409600
#define OFF_GAS 458752

__device__ __forceinline__ float clamp15(float x){ return fminf(15.f, fmaxf(-15.f, x)); }
__device__ __forceinline__ float rcp_(float x){ return __builtin_amdgcn_rcpf(x); }

// ---------------------------------------------------------------------------
// R10: the R9 counters (VGPR=64, WRITE 60MB, FETCH 566MB) prove the scratch
// spill SURVIVED R9: at 1024 thr/block the backend sees LDS 57KB -> 2 WG/CU
// feasible -> targets 8 waves/SIMD -> caps VGPR at 64 regardless of
// launch_bounds. Fix the geometry instead: 512 thr/block (8 waves, still
// 1 block/CU for the 64-block grid) + amdgpu_waves_per_eu(2,2) pins the
// budget at 256 VGPR/wave. Each thread does 2x work (12 gate rows in A,
// 12 o-channels in init/D). Eg moved LDS->registers (Ew[12] lives across
// the t-loop; -24KB LDS, -12 LDS reads/step); El values hoisted to regs.
// Peak live ~90 regs -> zero scratch expected.
// ---------------------------------------------------------------------------
__global__ __launch_bounds__(512) __attribute__((amdgpu_waves_per_eu(2, 2)))
void spat_kernel(
    const float* __restrict__ li,  const float* __restrict__ gi,
    const float* __restrict__ ls,  const float* __restrict__ gs,
    const float* __restrict__ dist,
    const float* __restrict__ la0, const float* __restrict__ ga0,
    const float* __restrict__ Wcl, const float* __restrict__ bcl,
    const float* __restrict__ Wll, const float* __restrict__ bll, const float* __restrict__ vl,
    const float* __restrict__ Wcg, const float* __restrict__ bcg,
    const float* __restrict__ Wlg, const float* __restrict__ blg, const float* __restrict__ vg,
    const float* __restrict__ Wih, const float* __restrict__ bih, const float* __restrict__ bhh,
    float* __restrict__ out)
{
    __shared__ float El[800];                // exp(2*hf_l), idx l*25+o
    __shared__ __align__(16) union {
        float wcg[6144];                     // Wcg staging (init only)
        struct {
            float sgred[512];
            float red[800];                  // idx l*25+o
            float gbuf[768];
            float xv[288];
            float cq[256];
        } p;
    } U;
    __shared__ float dstf[256];
    __shared__ float bsum[768];              // bih+bhh for used gate rows
    __shared__ float bcf[48];                // bll|blg
    __shared__ __align__(8) float2 fvl[24], fvg[24];   // (F_d, v_d) packed
    __shared__ float vlf[24], vgf[24], cbuf[2];

    const int b = blockIdx.x, tid = threadIdx.x;
    const int s = tid & 255, ogrp = tid >> 8;          // ogrp in {0,1}
    const int obase = ogrp * 12;

    // ---- small init (before first barrier) ----
    if (tid < 256) dstf[tid] = dist[b*256 + tid];
    if (tid < 24)  { vlf[tid] = vl[tid]; vgf[tid] = vg[tid]; }
    if (tid < 48)  bcf[tid] = (tid < 24) ? bll[tid] : blg[tid - 24];
    for (int k = tid; k < 768; k += 512) {
        const int wrow = k + ((k >= 256) ? 256 : 0);
        bsum[k] = bih[wrow] + bhh[wrow];
    }
    if (tid == 0)  { float s1 = 0.f; for (int d = 0; d < 24; d++) s1 += vl[d]; cbuf[0] = s1; }
    if (tid == 1)  { float s1 = 0.f; for (int d = 0; d < 24; d++) s1 += vg[d]; cbuf[1] = s1; }

    // ---- hf_g: thread (s, ogrp) accumulates 12 o's over c<24, j<32 ----
    float acc[12];
#pragma unroll
    for (int i = 0; i < 12; i++) acc[i] = bcg[obase + i];

    for (int hc = 0; hc < 3; hc++) {
        for (int k = tid; k < 6144; k += 512) {
            const int o = k >> 8, r = k & 255;
            U.wcg[k] = Wcg[o*768 + hc*256 + r];
        }
        __syncthreads();
        for (int cc = 0; cc < 8; cc++) {
            const int c = hc*8 + cc;
            const float4* gp = (const float4*)(gs + ((size_t)b*196608 + c*8192 + s*32));
#pragma unroll
            for (int h = 0; h < 2; h++) {            // two 16-float halves of j
                float gv[16];
#pragma unroll
                for (int m = 0; m < 4; m++) {
                    const float4 g = gp[h*4 + m];
                    gv[4*m] = g.x; gv[4*m+1] = g.y; gv[4*m+2] = g.z; gv[4*m+3] = g.w;
                }
#pragma unroll
                for (int i = 0; i < 12; i++) {
                    const float4* wp = (const float4*)(U.wcg + ((obase + i)*256 + cc*32)) + h*4;
                    float a = acc[i];
#pragma unroll
                    for (int m = 0; m < 4; m++) {
                        const float4 w = wp[m];
                        a = fmaf(w.x, gv[4*m],   a);
                        a = fmaf(w.y, gv[4*m+1], a);
                        a = fmaf(w.z, gv[4*m+2], a);
                        a = fmaf(w.w, gv[4*m+3], a);
                    }
                    acc[i] = a;
                }
            }
        }
        __syncthreads();
    }
    // Eg kept in registers for the whole t-loop (phase D reads exactly
    // the values this thread computed).
    float Ew[12];
#pragma unroll
    for (int i = 0; i < 12; i++) Ew[i] = __expf(2.f*clamp15(acc[i]));

    // ---- hf_l -> El (transposed: l*25+o) ----
    for (int k = tid; k < 768; k += 512) {
        const int o = k >> 5, l = k & 31;
        float a = bcl[o];
        for (int c = 0; c < 24; c++)
            a = fmaf(Wcl[o*24 + c], ls[b*768 + c*32 + l], a);
        El[l*25 + o] = __expf(2.f*clamp15(a));
    }

    // ---- x for t=0 (wcg union dead after hc-loop barrier) ----
    if (tid < 288) {
        if (tid < 32) U.p.xv[tid] = la0[b*32 + tid] * li[b*32 + tid];
        else { const int ss = tid - 32; U.p.xv[tid] = ga0[b*256 + ss] * gi[b*256 + ss]; }
    }
    __syncthreads();

    // per-thread s_l work items (constant over t): item0 = tid, item1 = tid+512
    const int l0 = tid / 24, o0 = tid - l0*24;
    const int k1 = tid + 512;
    const int l1 = k1 / 24,  o1 = k1 - l1*24;
    const float El0 = El[l0*25 + o0];
    const float El1 = (tid < 256) ? El[l1*25 + o1] : 0.f;

    const int u8 = tid & 7, slot = tid >> 3;   // phase A/C team layout
    const int rbase = slot*12;                 // 12 contiguous rows per slot

    for (int t = 0; t < T_; t++) {
        // prefetch next-step inputs for the fused x-build (wave0: li, wave1: gi)
        float liN = 0.f;
        float giN0 = 0.f, giN1 = 0.f, giN2 = 0.f, giN3 = 0.f;
        if (t < T_ - 1) {
            if (tid < 32) liN = li[(t+1)*2048 + b*32 + tid];
            else if (tid >= 64 && tid < 128) {
                const int lane = tid - 64;
                giN0 = gi[(t+1)*16384 + b*256 + lane];
                giN1 = gi[(t+1)*16384 + b*256 + lane + 64];
                giN2 = gi[(t+1)*16384 + b*256 + lane + 128];
                giN3 = gi[(t+1)*16384 + b*256 + lane + 192];
            }
        }

        // ---- A: gates GEMV, 8 lanes/row, 12 rows/slot, 3-chunk x cache ----
        {
            const float4* xp = (const float4*)U.p.xv;
            float ar[12];
#pragma unroll
            for (int k = 0; k < 12; k++) ar[k] = 0.f;
#pragma unroll
            for (int jc = 0; jc < 3; jc++) {
                const float4 x0 = xp[jc*24 + u8];
                const float4 x1 = xp[jc*24 + 8 + u8];
                const float4 x2 = xp[jc*24 + 16 + u8];
#pragma unroll
                for (int k = 0; k < 12; k++) {
                    const int row  = rbase + k;
                    const int wrow = row + ((row >= 256) ? 256 : 0);
                    const float4* wp = (const float4*)(Wih + wrow*288) + jc*24 + u8;
                    const float4 w0 = wp[0], w1 = wp[8], w2 = wp[16];
                    float a = ar[k];
                    a = fmaf(w0.x,x0.x,a); a = fmaf(w0.y,x0.y,a);
                    a = fmaf(w0.z,x0.z,a); a = fmaf(w0.w,x0.w,a);
                    a = fmaf(w1.x,x1.x,a); a = fmaf(w1.y,x1.y,a);
                    a = fmaf(w1.z,x1.z,a); a = fmaf(w1.w,x1.w,a);
                    a = fmaf(w2.x,x2.x,a); a = fmaf(w2.y,x2.y,a);
                    a = fmaf(w2.z,x2.z,a); a = fmaf(w2.w,x2.w,a);
                    ar[k] = a;
                }
            }
#pragma unroll
            for (int k = 0; k < 12; k++) {
                float a = ar[k];
                a += __shfl_xor(a, 1); a += __shfl_xor(a, 2); a += __shfl_xor(a, 4);
                if (u8 == 0) {
                    const int row = rbase + k;
                    U.p.gbuf[row] = a + bsum[row];
                }
            }
        }
        __syncthreads();

        // ---- B: c = sig(i)*tanh(g); h = sig(o)*tanh(c) ----
        if (tid < 256) {
            const float ig = U.p.gbuf[tid], gg = U.p.gbuf[256 + tid], ot = U.p.gbuf[512 + tid];
            const float sig_i = rcp_(1.f + __expf(-ig));
            const float th_g  = 1.f - 2.f*rcp_(1.f + __expf(2.f*clamp15(gg)));
            const float c     = sig_i * th_g;
            const float sig_o = rcp_(1.f + __expf(-ot));
            const float th_c  = 1.f - 2.f*rcp_(1.f + __expf(2.f*c));
            const float h     = sig_o * th_c;
            U.p.cq[tid] = c;
            out[t*16384 + b*256 + tid] = h;
            if (t == T_ - 1) out[OFF_CS + b*256 + tid] = c;
        }
        __syncthreads();

        // ---- C: 48 dots x 8-lane teams, conflict-free; F = exp(2y) ----
        if (tid < 384) {
            const int dot = slot;            // tid>>3 < 48
            const float* Wr = (dot < 24) ? (Wll + dot*256) : (Wlg + (dot - 24)*256);
            const float4* wp = (const float4*)Wr;
            const float4* cp = (const float4*)U.p.cq;
            float a0 = 0.f, a1 = 0.f;
#pragma unroll
            for (int j = 0; j < 8; j += 2) {
                const float4 w0 = wp[j*8 + u8],     c0 = cp[j*8 + u8];
                const float4 w1 = wp[(j+1)*8 + u8], c1 = cp[(j+1)*8 + u8];
                a0 = fmaf(w0.x,c0.x,a0); a0 = fmaf(w0.y,c0.y,a0);
                a0 = fmaf(w0.z,c0.z,a0); a0 = fmaf(w0.w,c0.w,a0);
                a1 = fmaf(w1.x,c1.x,a1); a1 = fmaf(w1.y,c1.y,a1);
                a1 = fmaf(w1.z,c1.z,a1); a1 = fmaf(w1.w,c1.w,a1);
            }
            float a = a0 + a1;
            a += __shfl_xor(a, 1); a += __shfl_xor(a, 2); a += __shfl_xor(a, 4);
            if (u8 == 0) {
                const float F = __expf(2.f*clamp15(a + bcf[dot]));
                if (dot < 24) fvl[dot] = make_float2(F, vlf[dot]);
                else          fvg[dot - 24] = make_float2(F, vgf[dot - 24]);
            }
        }
        __syncthreads();

        // ---- D: s_g partials (all, Ew in regs) + s_l partials ----
        {
            float a0 = 0.f;
#pragma unroll
            for (int d = 0; d < 24; d++) {
                const float2 p = fvg[d];
                const float r0  = rcp_(fmaf(Ew[0],  p.x, 1.f));
                const float r1  = rcp_(fmaf(Ew[1],  p.x, 1.f));
                const float r2  = rcp_(fmaf(Ew[2],  p.x, 1.f));
                const float r3  = rcp_(fmaf(Ew[3],  p.x, 1.f));
                const float r4  = rcp_(fmaf(Ew[4],  p.x, 1.f));
                const float r5  = rcp_(fmaf(Ew[5],  p.x, 1.f));
                const float r6  = rcp_(fmaf(Ew[6],  p.x, 1.f));
                const float r7  = rcp_(fmaf(Ew[7],  p.x, 1.f));
                const float r8  = rcp_(fmaf(Ew[8],  p.x, 1.f));
                const float r9  = rcp_(fmaf(Ew[9],  p.x, 1.f));
                const float r10 = rcp_(fmaf(Ew[10], p.x, 1.f));
                const float r11 = rcp_(fmaf(Ew[11], p.x, 1.f));
                const float sum = (((r0+r1)+(r2+r3)) + ((r4+r5)+(r6+r7))) + ((r8+r9)+(r10+r11));
                a0 = fmaf(p.y, sum, a0);
            }
            U.p.sgred[tid] = a0;
        }
        {
            // item 0 (all 512 threads)
            float b0 = 0.f, b1 = 0.f;
#pragma unroll
            for (int d = 0; d < 24; d += 2) {
                const float2 p0 = fvl[d], p1 = fvl[d+1];
                b0 = fmaf(p0.y, rcp_(fmaf(El0, p0.x, 1.f)), b0);
                b1 = fmaf(p1.y, rcp_(fmaf(El1, p1.x, 1.f)), b1);   // dummy for item1 path
            }
            // careful: b0 used El0 for even d, b1 used El1 -- WRONG pairing; redo below
            (void)b0; (void)b1;
        }
        {
            float b0 = 0.f, b1 = 0.f;
#pragma unroll
            for (int d = 0; d < 24; d += 2) {
                const float2 p0 = fvl[d], p1 = fvl[d+1];
                b0 = fmaf(p0.y, rcp_(fmaf(El0, p0.x, 1.f)), b0);
                b1 = fmaf(p1.y, rcp_(fmaf(El0, p1.x, 1.f)), b1);
            }
            U.p.red[l0*25 + o0] = b0 + b1;
            if (tid < 256) {
                float c0 = 0.f, c1 = 0.f;
#pragma unroll
                for (int d = 0; d < 24; d += 2) {
                    const float2 p0 = fvl[d], p1 = fvl[d+1];
                    c0 = fmaf(p0.y, rcp_(fmaf(El1, p0.x, 1.f)), c0);
                    c1 = fmaf(p1.y, rcp_(fmaf(El1, p1.x, 1.f)), c1);
                }
                U.p.red[l1*25 + o1] = c0 + c1;
            }
        }
        __syncthreads();

        // ---- E: both softmaxes + next-step x-build ----
        if (tid < 32) {                       // wave0: s_l softmax
            float tot = 0.f;
#pragma unroll
            for (int o2 = 0; o2 < 24; o2++) tot += U.p.red[tid*25 + o2];
            const float sv = 24.f*cbuf[0] - 2.f*tot;
            float m = sv;
#pragma unroll
            for (int mk = 16; mk >= 1; mk >>= 1) m = fmaxf(m, __shfl_xor(m, mk));
            const float e = __expf(sv - m);
            float ss = e;
#pragma unroll
            for (int mk = 16; mk >= 1; mk >>= 1) ss += __shfl_xor(ss, mk);
            const float r = e * rcp_(ss);
            out[OFF_LAS + t*2048 + b*32 + tid] = r;
            if (t < T_ - 1) U.p.xv[tid] = r * liN;
        } else if (tid >= 64 && tid < 128) {  // wave1: s_g softmax, 4 s/lane
            const int lane = tid - 64;
            float vv0, vv1, vv2, vv3;
            {
                const float t0 = U.p.sgred[lane]     + U.p.sgred[lane+256];
                const float t1 = U.p.sgred[lane+64]  + U.p.sgred[lane+320];
                const float t2 = U.p.sgred[lane+128] + U.p.sgred[lane+384];
                const float t3 = U.p.sgred[lane+192] + U.p.sgred[lane+448];
                vv0 = (1.f-LAMDA_)*(24.f*cbuf[1] - 2.f*t0) + LAMDA_*dstf[lane];
                vv1 = (1.f-LAMDA_)*(24.f*cbuf[1] - 2.f*t1) + LAMDA_*dstf[lane+64];
                vv2 = (1.f-LAMDA_)*(24.f*cbuf[1] - 2.f*t2) + LAMDA_*dstf[lane+128];
                vv3 = (1.f-LAMDA_)*(24.f*cbuf[1] - 2.f*t3) + LAMDA_*dstf[lane+192];
            }
            float m = fmaxf(fmaxf(vv0, vv1), fmaxf(vv2, vv3));
#pragma unroll
            for (int mk = 32; mk >= 1; mk >>= 1) m = fmaxf(m, __shfl_xor(m, mk));
            const float e0 = __expf(vv0 - m), e1 = __expf(vv1 - m);
            const float e2 = __expf(vv2 - m), e3 = __expf(vv3 - m);
            float ss = (e0 + e1) + (e2 + e3);
#pragma unroll
            for (int mk = 32; mk >= 1; mk >>= 1) ss += __shfl_xor(ss, mk);
            const float inv = rcp_(ss);
            const float r0 = e0*inv, r1 = e1*inv, r2 = e2*inv, r3 = e3*inv;
            float* og = out + OFF_GAS + t*16384 + b*256;
            og[lane] = r0; og[lane+64] = r1; og[lane+128] = r2; og[lane+192] = r3;
            if (t < T_ - 1) {
                U.p.xv[32+lane]     = r0 * giN0;
                U.p.xv[32+lane+64]  = r1 * giN1;
                U.p.xv[32+lane+128] = r2 * giN2;
                U.p.xv[32+lane+192] = r3 * giN3;
            }
        }
        __syncthreads();
    }
}

extern "C" void kernel_launch(void* const* d_in, const int* in_sizes, int n_in,
                              void* d_out, int out_size, void* d_ws, size_t ws_size,
                              hipStream_t stream)
{
    const float* li   = (const float*)d_in[0];
    const float* gi   = (const float*)d_in[1];
    const float* ls   = (const float*)d_in[2];
    const float* gs   = (const float*)d_in[3];
    const float* dist = (const float*)d_in[4];
    const float* la0  = (const float*)d_in[5];
    const float* ga0  = (const float*)d_in[6];
    const float* Wcl  = (const float*)d_in[7];
    const float* bcl  = (const float*)d_in[8];
    const float* Wll  = (const float*)d_in[9];
    const float* bll  = (const float*)d_in[10];
    const float* vl   = (const float*)d_in[11];
    const float* Wcg  = (const float*)d_in[12];
    const float* bcg  = (const float*)d_in[13];
    const float* Wlg  = (const float*)d_in[14];
    const float* blg  = (const float*)d_in[15];
    const float* vg   = (const float*)d_in[16];
    const float* Wih  = (const float*)d_in[17];
    const float* bih  = (const float*)d_in[18];
    const float* bhh  = (const float*)d_in[19];

    spat_kernel<<<64, 512, 0, stream>>>(li, gi, ls, gs, dist, la0, ga0,
                                        Wcl, bcl, Wll, bll, vl,
                                        Wcg, bcg, Wlg, blg, vg,
                                        Wih, bih, bhh, (float*)d_out);
}

// Round 2
// 542.483 us; speedup vs baseline: 1.9713x; 1.9713x over previous
//
#include <hip/hip_runtime.h>

#define T_     24
#define LAMDA_ 0.2f

// output layout (flat f32): outs[24,64,256] | cs[64,256] | las[24,64,32] | gas[24,64,256]
#define OFF_CS  393216
#define OFF_LAS 409600
#define OFF_GAS 458752

__device__ __forceinline__ float clamp15(float x){ return fminf(15.f, fmaxf(-15.f, x)); }
__device__ __forceinline__ float rcp_(float x){ return __builtin_amdgcn_rcpf(x); }

// ---------------------------------------------------------------------------
// R11: R10 regressed (975us): 512thr halved latency hiding (2 waves/SIMD) and
// STILL spilled ~14dw/thread/step (WRITE 45MB) -- full unroll lets the
// scheduler hoist ~100 loads, so it spills long-lived regs (Ew[12]!) which
// phase D then reloads inside the 24-deep d-loop. Back to 1024 thr
// (4 waves/SIMD). Spill killed from both sides:
//  (a) raise cap: LDS padded >80KB (free: grid=64 -> 1 block/CU at runtime
//      regardless) + __launch_bounds__(1024,4) -> backend occupancy target
//      16 waves/CU -> 128-VGPR budget instead of 64.
//  (b) bound demand: Eg/El live in LDS (re-read per step, 7 ds_reads),
//      NAMED accumulators ar0..ar5 (no runtime-indexed arrays -> no scratch),
//      sched_barrier(0) every 2 rows in phase A caps in-flight weight loads
//      at 6 float4 (24 VGPR). Designed peak ~60 regs: fits even a 64 cap.
// Predicted: WRITE 45MB->3.6MB, FETCH 381->~100MB, dur 200-350us.
// ---------------------------------------------------------------------------
__global__ __launch_bounds__(1024, 4) void spat_kernel(
    const float* __restrict__ li,  const float* __restrict__ gi,
    const float* __restrict__ ls,  const float* __restrict__ gs,
    const float* __restrict__ dist,
    const float* __restrict__ la0, const float* __restrict__ ga0,
    const float* __restrict__ Wcl, const float* __restrict__ bcl,
    const float* __restrict__ Wll, const float* __restrict__ bll, const float* __restrict__ vl,
    const float* __restrict__ Wcg, const float* __restrict__ bcg,
    const float* __restrict__ Wlg, const float* __restrict__ blg, const float* __restrict__ vg,
    const float* __restrict__ Wih, const float* __restrict__ bih, const float* __restrict__ bhh,
    float* __restrict__ out)
{
    __shared__ float Eg[6144];               // exp(2*hf_g[o][s]), o<24, s<256
    __shared__ float El[800];                // exp(2*hf_l), idx l*25+o
    __shared__ __align__(16) union {
        float wcg[6144];                     // Wcg staging (init only)
        struct {
            float sgred[1024];
            float red[800];                  // idx l*25+o
            float gbuf[768];
            float xv[288];
            float cq[256];
        } p;
    } U;
    __shared__ float dstf[256];
    __shared__ float bsum[768];              // bih+bhh for used gate rows
    __shared__ float bcf[48];                // bll|blg
    __shared__ __align__(8) float2 fvl[24], fvg[24];   // (F_d, v_d) packed
    __shared__ float vlf[24], vgf[24], cbuf[2];
    // occupancy-shaping pad: pushes LDS past 80KB so the backend targets
    // 1 WG/CU (16 waves) -> 128-VGPR budget. Runtime-free: grid=64 blocks
    // on 256 CUs is 1 block/CU regardless.
    __shared__ float ldspad[10240];

    const int b = blockIdx.x, tid = threadIdx.x;
    const int s = tid & 255, ogrp = tid >> 8;

    // keep-alive for ldspad (branch never taken; blockIdx unknowable)
    if (__builtin_expect((int)blockIdx.x == -1, 0)) {
        ldspad[tid] = bcg[0];
        out[0] = ldspad[tid ^ 1];
    }

    // ---- small init (before first barrier) ----
    if (tid < 256) dstf[tid] = dist[b*256 + tid];
    if (tid < 24)  { vlf[tid] = vl[tid]; vgf[tid] = vg[tid]; }
    if (tid < 48)  bcf[tid] = (tid < 24) ? bll[tid] : blg[tid - 24];
    if (tid < 768) {
        const int wrow = tid + ((tid >= 256) ? 256 : 0);
        bsum[tid] = bih[wrow] + bhh[wrow];
    }
    if (tid == 0)  { float s1 = 0.f; for (int d = 0; d < 24; d++) s1 += vl[d]; cbuf[0] = s1; }
    if (tid == 1)  { float s1 = 0.f; for (int d = 0; d < 24; d++) s1 += vg[d]; cbuf[1] = s1; }

    // ---- hf_g: thread (s, ogrp) accumulates 6 o's over c<24, j<32 ----
    float acc[6];
#pragma unroll
    for (int i = 0; i < 6; i++) acc[i] = bcg[ogrp*6 + i];

    for (int hc = 0; hc < 3; hc++) {
        for (int k = tid; k < 6144; k += 1024) {
            const int o = k >> 8, r = k & 255;
            U.wcg[k] = Wcg[o*768 + hc*256 + r];
        }
        __syncthreads();
        for (int cc = 0; cc < 8; cc++) {
            const int c = hc*8 + cc;
            const float4* gp = (const float4*)(gs + ((size_t)b*196608 + c*8192 + s*32));
#pragma unroll
            for (int h = 0; h < 2; h++) {            // two 16-float halves of j
                float gv[16];
#pragma unroll
                for (int m = 0; m < 4; m++) {
                    const float4 g = gp[h*4 + m];
                    gv[4*m] = g.x; gv[4*m+1] = g.y; gv[4*m+2] = g.z; gv[4*m+3] = g.w;
                }
#pragma unroll
                for (int i = 0; i < 6; i++) {
                    const float4* wp = (const float4*)(U.wcg + ((ogrp*6 + i)*256 + cc*32)) + h*4;
                    float a = acc[i];
#pragma unroll
                    for (int m = 0; m < 4; m++) {
                        const float4 w = wp[m];
                        a = fmaf(w.x, gv[4*m],   a);
                        a = fmaf(w.y, gv[4*m+1], a);
                        a = fmaf(w.z, gv[4*m+2], a);
                        a = fmaf(w.w, gv[4*m+3], a);
                    }
                    acc[i] = a;
                }
            }
        }
        __syncthreads();
    }
#pragma unroll
    for (int i = 0; i < 6; i++) Eg[(ogrp*6 + i)*256 + s] = __expf(2.f*clamp15(acc[i]));

    // ---- hf_l -> El (transposed: l*25+o) ----
    if (tid < 768) {
        const int o = tid >> 5, l = tid & 31;
        float a = bcl[o];
        for (int c = 0; c < 24; c++)
            a = fmaf(Wcl[o*24 + c], ls[b*768 + c*32 + l], a);
        El[l*25 + o] = __expf(2.f*clamp15(a));
    }

    // ---- x for t=0 (wcg union dead after hc-loop barrier) ----
    if (tid < 288) {
        if (tid < 32) U.p.xv[tid] = la0[b*32 + tid] * li[b*32 + tid];
        else { const int ss = tid - 32; U.p.xv[tid] = ga0[b*256 + ss] * gi[b*256 + ss]; }
    }
    __syncthreads();

    const int u8 = tid & 7, slot = tid >> 3;   // phase A/C team layout
    const int rbase = slot*6;                  // 6 contiguous rows per slot

    for (int t = 0; t < T_; t++) {
        // prefetch next-step inputs for the fused x-build (wave0: li, wave1: gi)
        float liN = 0.f;
        float giN0 = 0.f, giN1 = 0.f, giN2 = 0.f, giN3 = 0.f;
        if (t < T_ - 1) {
            if (tid < 32) liN = li[(t+1)*2048 + b*32 + tid];
            else if (tid >= 64 && tid < 128) {
                const int lane = tid - 64;
                giN0 = gi[(t+1)*16384 + b*256 + lane];
                giN1 = gi[(t+1)*16384 + b*256 + lane + 64];
                giN2 = gi[(t+1)*16384 + b*256 + lane + 128];
                giN3 = gi[(t+1)*16384 + b*256 + lane + 192];
            }
        }

        // ---- A: gates GEMV, 8 lanes/row, named accumulators, bounded
        //      in-flight loads (sched_barrier every 2 rows) ----
        {
            const float4* xp = (const float4*)U.p.xv;
            float ar0 = 0.f, ar1 = 0.f, ar2 = 0.f, ar3 = 0.f, ar4 = 0.f, ar5 = 0.f;
#pragma unroll 1
            for (int jc = 0; jc < 3; jc++) {
                const float4 x0 = xp[jc*24 + u8];
                const float4 x1 = xp[jc*24 + 8 + u8];
                const float4 x2 = xp[jc*24 + 16 + u8];

#define KROW(kk, AR) { \
                const int row_ = rbase + (kk); \
                const int wrow_ = row_ + ((row_ >= 256) ? 256 : 0); \
                const float4* wp_ = (const float4*)(Wih + wrow_*288) + jc*24 + u8; \
                const float4 w0_ = wp_[0], w1_ = wp_[8], w2_ = wp_[16]; \
                float a_ = AR; \
                a_ = fmaf(w0_.x,x0.x,a_); a_ = fmaf(w0_.y,x0.y,a_); \
                a_ = fmaf(w0_.z,x0.z,a_); a_ = fmaf(w0_.w,x0.w,a_); \
                a_ = fmaf(w1_.x,x1.x,a_); a_ = fmaf(w1_.y,x1.y,a_); \
                a_ = fmaf(w1_.z,x1.z,a_); a_ = fmaf(w1_.w,x1.w,a_); \
                a_ = fmaf(w2_.x,x2.x,a_); a_ = fmaf(w2_.y,x2.y,a_); \
                a_ = fmaf(w2_.z,x2.z,a_); a_ = fmaf(w2_.w,x2.w,a_); \
                AR = a_; }

                KROW(0, ar0) KROW(1, ar1)
                __builtin_amdgcn_sched_barrier(0);
                KROW(2, ar2) KROW(3, ar3)
                __builtin_amdgcn_sched_barrier(0);
                KROW(4, ar4) KROW(5, ar5)
                __builtin_amdgcn_sched_barrier(0);
#undef KROW
            }
            {
                float a_;
#define RED(kk, AR) { a_ = AR; \
                a_ += __shfl_xor(a_, 1); a_ += __shfl_xor(a_, 2); a_ += __shfl_xor(a_, 4); \
                if (u8 == 0) { const int row_ = rbase + (kk); U.p.gbuf[row_] = a_ + bsum[row_]; } }
                RED(0, ar0) RED(1, ar1) RED(2, ar2) RED(3, ar3) RED(4, ar4) RED(5, ar5)
#undef RED
            }
        }
        __syncthreads();

        // ---- B: c = sig(i)*tanh(g); h = sig(o)*tanh(c) ----
        if (tid < 256) {
            const float ig = U.p.gbuf[tid], gg = U.p.gbuf[256 + tid], ot = U.p.gbuf[512 + tid];
            const float sig_i = rcp_(1.f + __expf(-ig));
            const float th_g  = 1.f - 2.f*rcp_(1.f + __expf(2.f*clamp15(gg)));
            const float c     = sig_i * th_g;
            const float sig_o = rcp_(1.f + __expf(-ot));
            const float th_c  = 1.f - 2.f*rcp_(1.f + __expf(2.f*c));
            const float h     = sig_o * th_c;
            U.p.cq[tid] = c;
            out[t*16384 + b*256 + tid] = h;
            if (t == T_ - 1) out[OFF_CS + b*256 + tid] = c;
        }
        __syncthreads();

        // ---- C: 48 dots x 8-lane teams, conflict-free; F = exp(2y) ----
        if (tid < 384) {
            const int dot = slot;            // tid>>3 < 48
            const float* Wr = (dot < 24) ? (Wll + dot*256) : (Wlg + (dot - 24)*256);
            const float4* wp = (const float4*)Wr;
            const float4* cp = (const float4*)U.p.cq;
            float a0 = 0.f, a1 = 0.f;
#pragma unroll
            for (int j = 0; j < 8; j += 2) {
                const float4 w0 = wp[j*8 + u8],     c0 = cp[j*8 + u8];
                const float4 w1 = wp[(j+1)*8 + u8], c1 = cp[(j+1)*8 + u8];
                a0 = fmaf(w0.x,c0.x,a0); a0 = fmaf(w0.y,c0.y,a0);
                a0 = fmaf(w0.z,c0.z,a0); a0 = fmaf(w0.w,c0.w,a0);
                a1 = fmaf(w1.x,c1.x,a1); a1 = fmaf(w1.y,c1.y,a1);
                a1 = fmaf(w1.z,c1.z,a1); a1 = fmaf(w1.w,c1.w,a1);
            }
            float a = a0 + a1;
            a += __shfl_xor(a, 1); a += __shfl_xor(a, 2); a += __shfl_xor(a, 4);
            if (u8 == 0) {
                const float F = __expf(2.f*clamp15(a + bcf[dot]));
                if (dot < 24) fvl[dot] = make_float2(F, vlf[dot]);
                else          fvg[dot - 24] = make_float2(F, vgf[dot - 24]);
            }
        }
        __syncthreads();

        // ---- D: s_g partials (all) + s_l partials (tid<768); Ew read fresh
        //      from LDS each step (ephemeral regs, never spill-worthy) ----
        {
            float Ew[6];
#pragma unroll
            for (int i = 0; i < 6; i++) Ew[i] = Eg[(ogrp*6 + i)*256 + s];
            float a0 = 0.f;
#pragma unroll
            for (int d = 0; d < 24; d++) {
                const float2 p = fvg[d];
                const float r0 = rcp_(fmaf(Ew[0], p.x, 1.f));
                const float r1 = rcp_(fmaf(Ew[1], p.x, 1.f));
                const float r2 = rcp_(fmaf(Ew[2], p.x, 1.f));
                const float r3 = rcp_(fmaf(Ew[3], p.x, 1.f));
                const float r4 = rcp_(fmaf(Ew[4], p.x, 1.f));
                const float r5 = rcp_(fmaf(Ew[5], p.x, 1.f));
                a0 = fmaf(p.y, ((r0 + r1) + (r2 + r3)) + (r4 + r5), a0);
            }
            U.p.sgred[tid] = a0;
        }
        if (tid < 768) {
            const int l = tid / 24, o = tid - l*24;
            const float E = El[l*25 + o];
            float b0 = 0.f, b1 = 0.f;
#pragma unroll
            for (int d = 0; d < 24; d += 2) {
                const float2 p0 = fvl[d], p1 = fvl[d+1];
                b0 = fmaf(p0.y, rcp_(fmaf(E, p0.x, 1.f)), b0);
                b1 = fmaf(p1.y, rcp_(fmaf(E, p1.x, 1.f)), b1);
            }
            U.p.red[l*25 + o] = b0 + b1;
        }
        __syncthreads();

        // ---- E: both softmaxes + next-step x-build ----
        if (tid < 32) {                       // wave0: s_l softmax
            float tot = 0.f;
#pragma unroll
            for (int o2 = 0; o2 < 24; o2++) tot += U.p.red[tid*25 + o2];
            const float sv = 24.f*cbuf[0] - 2.f*tot;
            float m = sv;
#pragma unroll
            for (int mk = 16; mk >= 1; mk >>= 1) m = fmaxf(m, __shfl_xor(m, mk));
            const float e = __expf(sv - m);
            float ss = e;
#pragma unroll
            for (int mk = 16; mk >= 1; mk >>= 1) ss += __shfl_xor(ss, mk);
            const float r = e * rcp_(ss);
            out[OFF_LAS + t*2048 + b*32 + tid] = r;
            if (t < T_ - 1) U.p.xv[tid] = r * liN;
        } else if (tid >= 64 && tid < 128) {  // wave1: s_g softmax, 4 s/lane
            const int lane = tid - 64;
            float vv0, vv1, vv2, vv3;
            {
                const float t0 = U.p.sgred[lane]     + U.p.sgred[256+lane]     + U.p.sgred[512+lane]     + U.p.sgred[768+lane];
                const float t1 = U.p.sgred[lane+64]  + U.p.sgred[256+lane+64]  + U.p.sgred[512+lane+64]  + U.p.sgred[768+lane+64];
                const float t2 = U.p.sgred[lane+128] + U.p.sgred[256+lane+128] + U.p.sgred[512+lane+128] + U.p.sgred[768+lane+128];
                const float t3 = U.p.sgred[lane+192] + U.p.sgred[256+lane+192] + U.p.sgred[512+lane+192] + U.p.sgred[768+lane+192];
                vv0 = (1.f-LAMDA_)*(24.f*cbuf[1] - 2.f*t0) + LAMDA_*dstf[lane];
                vv1 = (1.f-LAMDA_)*(24.f*cbuf[1] - 2.f*t1) + LAMDA_*dstf[lane+64];
                vv2 = (1.f-LAMDA_)*(24.f*cbuf[1] - 2.f*t2) + LAMDA_*dstf[lane+128];
                vv3 = (1.f-LAMDA_)*(24.f*cbuf[1] - 2.f*t3) + LAMDA_*dstf[lane+192];
            }
            float m = fmaxf(fmaxf(vv0, vv1), fmaxf(vv2, vv3));
#pragma unroll
            for (int mk = 32; mk >= 1; mk >>= 1) m = fmaxf(m, __shfl_xor(m, mk));
            const float e0 = __expf(vv0 - m), e1 = __expf(vv1 - m);
            const float e2 = __expf(vv2 - m), e3 = __expf(vv3 - m);
            float ss = (e0 + e1) + (e2 + e3);
#pragma unroll
            for (int mk = 32; mk >= 1; mk >>= 1) ss += __shfl_xor(ss, mk);
            const float inv = rcp_(ss);
            const float r0 = e0*inv, r1 = e1*inv, r2 = e2*inv, r3 = e3*inv;
            float* og = out + OFF_GAS + t*16384 + b*256;
            og[lane] = r0; og[lane+64] = r1; og[lane+128] = r2; og[lane+192] = r3;
            if (t < T_ - 1) {
                U.p.xv[32+lane]     = r0 * giN0;
                U.p.xv[32+lane+64]  = r1 * giN1;
                U.p.xv[32+lane+128] = r2 * giN2;
                U.p.xv[32+lane+192] = r3 * giN3;
            }
        }
        __syncthreads();
    }
}

extern "C" void kernel_launch(void* const* d_in, const int* in_sizes, int n_in,
                              void* d_out, int out_size, void* d_ws, size_t ws_size,
                              hipStream_t stream)
{
    const float* li   = (const float*)d_in[0];
    const float* gi   = (const float*)d_in[1];
    const float* ls   = (const float*)d_in[2];
    const float* gs   = (const float*)d_in[3];
    const float* dist = (const float*)d_in[4];
    const float* la0  = (const float*)d_in[5];
    const float* ga0  = (const float*)d_in[6];
    const float* Wcl  = (const float*)d_in[7];
    const float* bcl  = (const float*)d_in[8];
    const float* Wll  = (const float*)d_in[9];
    const float* bll  = (const float*)d_in[10];
    const float* vl   = (const float*)d_in[11];
    const float* Wcg  = (const float*)d_in[12];
    const float* bcg  = (const float*)d_in[13];
    const float* Wlg  = (const float*)d_in[14];
    const float* blg  = (const float*)d_in[15];
    const float* vg   = (const float*)d_in[16];
    const float* Wih  = (const float*)d_in[17];
    const float* bih  = (const float*)d_in[18];
    const float* bhh  = (const float*)d_in[19];

    spat_kernel<<<64, 1024, 0, stream>>>(li, gi, ls, gs, dist, la0, ga0,
                                         Wcl, bcl, Wll, bll, vl,
                                         Wcg, bcg, Wlg, blg, vg,
                                         Wih, bih, bhh, (float*)d_out);
}

// Round 3
// 506.169 us; speedup vs baseline: 2.1128x; 1.0717x over previous
//
#include <hip/hip_runtime.h>

#define T_     24
#define LAMDA_ 0.2f

// output layout (flat f32): outs[24,64,256] | cs[64,256] | las[24,64,32] | gas[24,64,256]
#define OFF_CS  393216
#define OFF_LAS 409600
#define OFF_GAS 458752

__device__ __forceinline__ float clamp15(float x){ return fminf(15.f, fmaxf(-15.f, x)); }
__device__ __forceinline__ float rcp_(float x){ return __builtin_amdgcn_rcpf(x); }

// ---------------------------------------------------------------------------
// R12: R11 (451us) killed the spill; active-CU VALUBusy ~46%, rest latency.
// This round:
//  (1) pair-merge rational trick halves v_rcp count in phase D:
//      v_a/(1+z w_a)+v_b/(1+z w_b) = (A0+z A1)/(1+z B1+z^2 B2); coeffs built
//      in phase C via __shfl_xor(F,8) between partner dot-teams (no extra
//      barrier). inf-safe: den->inf => rcp=0, num finite => term->0 (correct).
//  (2) all outputs buffered in LDS (outb/gasb/lasb/csb, 52KB) and flushed
//      after the t-loop -> no global-store vmcnt drain at in-loop barriers.
//      LDS total ~108KB: keeps 1 WG/CU shaping naturally (pad deleted).
//  (3) s_l partials: 1024 threads (32 groups x 24 lanes) + shfl-reduce ->
//      phase E reads 1 value instead of 24.
//  (4) phase A fences relaxed 3->2 groups/jc (9 loads in flight, 36 VGPR;
//      budget at 16 waves/CU is 128 so this cannot spill).
// Tripwire: WRITE_SIZE must be ~3.3MB. If >10MB the spill returned.
// ---------------------------------------------------------------------------
__global__ __launch_bounds__(1024, 4) void spat_kernel(
    const float* __restrict__ li,  const float* __restrict__ gi,
    const float* __restrict__ ls,  const float* __restrict__ gs,
    const float* __restrict__ dist,
    const float* __restrict__ la0, const float* __restrict__ ga0,
    const float* __restrict__ Wcl, const float* __restrict__ bcl,
    const float* __restrict__ Wll, const float* __restrict__ bll, const float* __restrict__ vl,
    const float* __restrict__ Wcg, const float* __restrict__ bcg,
    const float* __restrict__ Wlg, const float* __restrict__ blg, const float* __restrict__ vg,
    const float* __restrict__ Wih, const float* __restrict__ bih, const float* __restrict__ bhh,
    float* __restrict__ out)
{
    __shared__ float Eg[6144];               // exp(2*hf_g[o][s]), o<24, s<256
    __shared__ float El[800];                // exp(2*hf_l), idx l*25+o
    __shared__ float outb[6144];             // h outputs  [t][i]
    __shared__ float gasb[6144];             // gas        [t][s]
    __shared__ float lasb[768];              // las        [t][l]
    __shared__ float csb[256];               // c at t=23
    __shared__ __align__(16) union {
        float wcg[6144];                     // Wcg staging (init only)
        struct {
            float sgred[1024];
            float gbuf[768];
            float xv[288];
            float cq[256];
            float slg[32];
        } p;
    } U;
    __shared__ float dstf[256];
    __shared__ float bsum[768];              // bih+bhh for used gate rows
    __shared__ float bcf[48];                // bll|blg
    __shared__ __align__(16) float4 pl4[12], pg4[12];  // pair coeffs (A0,A1,B1,B2)
    __shared__ float vlf[24], vgf[24], cbuf[2];

    const int b = blockIdx.x, tid = threadIdx.x;
    const int s = tid & 255, ogrp = tid >> 8;

    // ---- small init (before first barrier) ----
    if (tid < 256) dstf[tid] = dist[b*256 + tid];
    if (tid < 24)  { vlf[tid] = vl[tid]; vgf[tid] = vg[tid]; }
    if (tid < 48)  bcf[tid] = (tid < 24) ? bll[tid] : blg[tid - 24];
    if (tid < 768) {
        const int wrow = tid + ((tid >= 256) ? 256 : 0);
        bsum[tid] = bih[wrow] + bhh[wrow];
    }
    if (tid == 0)  { float s1 = 0.f; for (int d = 0; d < 24; d++) s1 += vl[d]; cbuf[0] = s1; }
    if (tid == 1)  { float s1 = 0.f; for (int d = 0; d < 24; d++) s1 += vg[d]; cbuf[1] = s1; }

    // ---- hf_g: thread (s, ogrp) accumulates 6 o's over c<24, j<32 ----
    float acc[6];
#pragma unroll
    for (int i = 0; i < 6; i++) acc[i] = bcg[ogrp*6 + i];

    for (int hc = 0; hc < 3; hc++) {
        for (int k = tid; k < 6144; k += 1024) {
            const int o = k >> 8, r = k & 255;
            U.wcg[k] = Wcg[o*768 + hc*256 + r];
        }
        __syncthreads();
        for (int cc = 0; cc < 8; cc++) {
            const int c = hc*8 + cc;
            const float4* gp = (const float4*)(gs + ((size_t)b*196608 + c*8192 + s*32));
#pragma unroll
            for (int h = 0; h < 2; h++) {            // two 16-float halves of j
                float gv[16];
#pragma unroll
                for (int m = 0; m < 4; m++) {
                    const float4 g = gp[h*4 + m];
                    gv[4*m] = g.x; gv[4*m+1] = g.y; gv[4*m+2] = g.z; gv[4*m+3] = g.w;
                }
#pragma unroll
                for (int i = 0; i < 6; i++) {
                    const float4* wp = (const float4*)(U.wcg + ((ogrp*6 + i)*256 + cc*32)) + h*4;
                    float a = acc[i];
#pragma unroll
                    for (int m = 0; m < 4; m++) {
                        const float4 w = wp[m];
                        a = fmaf(w.x, gv[4*m],   a);
                        a = fmaf(w.y, gv[4*m+1], a);
                        a = fmaf(w.z, gv[4*m+2], a);
                        a = fmaf(w.w, gv[4*m+3], a);
                    }
                    acc[i] = a;
                }
            }
        }
        __syncthreads();
    }
#pragma unroll
    for (int i = 0; i < 6; i++) Eg[(ogrp*6 + i)*256 + s] = __expf(2.f*clamp15(acc[i]));

    // ---- hf_l -> El (transposed: l*25+o) ----
    if (tid < 768) {
        const int o = tid >> 5, l = tid & 31;
        float a = bcl[o];
        for (int c = 0; c < 24; c++)
            a = fmaf(Wcl[o*24 + c], ls[b*768 + c*32 + l], a);
        El[l*25 + o] = __expf(2.f*clamp15(a));
    }

    // ---- x for t=0 (wcg union dead after hc-loop barrier) ----
    if (tid < 288) {
        if (tid < 32) U.p.xv[tid] = la0[b*32 + tid] * li[b*32 + tid];
        else { const int ss = tid - 32; U.p.xv[tid] = ga0[b*256 + ss] * gi[b*256 + ss]; }
    }
    __syncthreads();

    const int u8 = tid & 7, slot = tid >> 3;   // phase A/C team layout
    const int rbase = slot*6;                  // 6 contiguous rows per slot
    const int lg = tid >> 5, ol = tid & 31;    // phase D s_l layout (32 groups x 32)

    for (int t = 0; t < T_; t++) {
        // prefetch next-step inputs for the fused x-build (wave0: li, wave1: gi)
        float liN = 0.f;
        float giN0 = 0.f, giN1 = 0.f, giN2 = 0.f, giN3 = 0.f;
        if (t < T_ - 1) {
            if (tid < 32) liN = li[(t+1)*2048 + b*32 + tid];
            else if (tid >= 64 && tid < 128) {
                const int lane = tid - 64;
                giN0 = gi[(t+1)*16384 + b*256 + lane];
                giN1 = gi[(t+1)*16384 + b*256 + lane + 64];
                giN2 = gi[(t+1)*16384 + b*256 + lane + 128];
                giN3 = gi[(t+1)*16384 + b*256 + lane + 192];
            }
        }

        // ---- A: gates GEMV, 8 lanes/row, named accumulators, 2 fence
        //      groups of 3 rows (9 loads in flight) ----
        {
            const float4* xp = (const float4*)U.p.xv;
            float ar0 = 0.f, ar1 = 0.f, ar2 = 0.f, ar3 = 0.f, ar4 = 0.f, ar5 = 0.f;
#pragma unroll 1
            for (int jc = 0; jc < 3; jc++) {
                const float4 x0 = xp[jc*24 + u8];
                const float4 x1 = xp[jc*24 + 8 + u8];
                const float4 x2 = xp[jc*24 + 16 + u8];

#define KROW(kk, AR) { \
                const int row_ = rbase + (kk); \
                const int wrow_ = row_ + ((row_ >= 256) ? 256 : 0); \
                const float4* wp_ = (const float4*)(Wih + wrow_*288) + jc*24 + u8; \
                const float4 w0_ = wp_[0], w1_ = wp_[8], w2_ = wp_[16]; \
                float a_ = AR; \
                a_ = fmaf(w0_.x,x0.x,a_); a_ = fmaf(w0_.y,x0.y,a_); \
                a_ = fmaf(w0_.z,x0.z,a_); a_ = fmaf(w0_.w,x0.w,a_); \
                a_ = fmaf(w1_.x,x1.x,a_); a_ = fmaf(w1_.y,x1.y,a_); \
                a_ = fmaf(w1_.z,x1.z,a_); a_ = fmaf(w1_.w,x1.w,a_); \
                a_ = fmaf(w2_.x,x2.x,a_); a_ = fmaf(w2_.y,x2.y,a_); \
                a_ = fmaf(w2_.z,x2.z,a_); a_ = fmaf(w2_.w,x2.w,a_); \
                AR = a_; }

                KROW(0, ar0) KROW(1, ar1) KROW(2, ar2)
                __builtin_amdgcn_sched_barrier(0);
                KROW(3, ar3) KROW(4, ar4) KROW(5, ar5)
                __builtin_amdgcn_sched_barrier(0);
#undef KROW
            }
            {
                float a_;
#define RED(kk, AR) { a_ = AR; \
                a_ += __shfl_xor(a_, 1); a_ += __shfl_xor(a_, 2); a_ += __shfl_xor(a_, 4); \
                if (u8 == 0) { const int row_ = rbase + (kk); U.p.gbuf[row_] = a_ + bsum[row_]; } }
                RED(0, ar0) RED(1, ar1) RED(2, ar2) RED(3, ar3) RED(4, ar4) RED(5, ar5)
#undef RED
            }
        }
        __syncthreads();

        // ---- B: c = sig(i)*tanh(g); h = sig(o)*tanh(c); h,c -> LDS only ----
        if (tid < 256) {
            const float ig = U.p.gbuf[tid], gg = U.p.gbuf[256 + tid], ot = U.p.gbuf[512 + tid];
            const float sig_i = rcp_(1.f + __expf(-ig));
            const float th_g  = 1.f - 2.f*rcp_(1.f + __expf(2.f*clamp15(gg)));
            const float c     = sig_i * th_g;
            const float sig_o = rcp_(1.f + __expf(-ot));
            const float th_c  = 1.f - 2.f*rcp_(1.f + __expf(2.f*c));
            const float h     = sig_o * th_c;
            U.p.cq[tid] = c;
            outb[t*256 + tid] = h;
            if (t == T_ - 1) csb[tid] = c;
        }
        __syncthreads();

        // ---- C: 48 dots x 8-lane teams; F = exp(2y); build pair coeffs
        //      via shfl_xor(.,8) between partner teams (even slot writes) ----
        if (tid < 384) {
            const int dot = slot;            // tid>>3 < 48
            const float* Wr = (dot < 24) ? (Wll + dot*256) : (Wlg + (dot - 24)*256);
            const float4* wp = (const float4*)Wr;
            const float4* cp = (const float4*)U.p.cq;
            float a0 = 0.f, a1 = 0.f;
#pragma unroll
            for (int j = 0; j < 8; j += 2) {
                const float4 w0 = wp[j*8 + u8],     c0 = cp[j*8 + u8];
                const float4 w1 = wp[(j+1)*8 + u8], c1 = cp[(j+1)*8 + u8];
                a0 = fmaf(w0.x,c0.x,a0); a0 = fmaf(w0.y,c0.y,a0);
                a0 = fmaf(w0.z,c0.z,a0); a0 = fmaf(w0.w,c0.w,a0);
                a1 = fmaf(w1.x,c1.x,a1); a1 = fmaf(w1.y,c1.y,a1);
                a1 = fmaf(w1.z,c1.z,a1); a1 = fmaf(w1.w,c1.w,a1);
            }
            float a = a0 + a1;
            a += __shfl_xor(a, 1); a += __shfl_xor(a, 2); a += __shfl_xor(a, 4);
            // all 8 lanes of the team now hold the dot sum
            const float F  = __expf(2.f*clamp15(a + bcf[dot]));
            const float v  = (dot < 24) ? vlf[dot] : vgf[dot - 24];
            const float Fo = __shfl_xor(F, 8);          // partner team (slot^1)
            const float vo = (dot < 24) ? vlf[dot ^ 1] : vgf[(dot ^ 1) - 24];
            if ((tid & 15) == 0) {                      // lane 0 of even slot
                const float A0 = v + vo;
                const float A1 = fmaf(v, Fo, vo * F);
                const float B1 = F + Fo;
                const float B2 = F * Fo;
                const int P = slot >> 1;                // 0..23
                if (P < 12) pl4[P]      = make_float4(A0, A1, B1, B2);
                else        pg4[P - 12] = make_float4(A0, A1, B1, B2);
            }
        }
        __syncthreads();

        // ---- D: s_g partials (all threads, 6 o, 12 pairs) +
        //         s_l partials (32 groups x 24 lanes, 12 pairs, shfl-reduce) ----
        {
            float z[6], z2[6];
#pragma unroll
            for (int i = 0; i < 6; i++) {
                z[i]  = Eg[(ogrp*6 + i)*256 + s];
                z2[i] = z[i]*z[i];
            }
            float a0 = 0.f;
#pragma unroll 4
            for (int p = 0; p < 12; p++) {
                const float4 q = pg4[p];
#pragma unroll
                for (int i = 0; i < 6; i++) {
                    const float num = fmaf(z[i],  q.y, q.x);
                    const float den = fmaf(z2[i], q.w, fmaf(z[i], q.z, 1.f));
                    a0 = fmaf(num, rcp_(den), a0);
                }
            }
            U.p.sgred[tid] = a0;
        }
        {
            float bsl = 0.f;
            if (ol < 24) {
                const float E  = El[lg*25 + ol];
                const float E2 = E*E;
#pragma unroll 4
                for (int p = 0; p < 12; p++) {
                    const float4 q = pl4[p];
                    const float num = fmaf(E,  q.y, q.x);
                    const float den = fmaf(E2, q.w, fmaf(E, q.z, 1.f));
                    bsl = fmaf(num, rcp_(den), bsl);
                }
            }
            bsl += __shfl_xor(bsl, 1);  bsl += __shfl_xor(bsl, 2);
            bsl += __shfl_xor(bsl, 4);  bsl += __shfl_xor(bsl, 8);
            bsl += __shfl_xor(bsl, 16);
            if (ol == 0) U.p.slg[lg] = bsl;
        }
        __syncthreads();

        // ---- E: both softmaxes + next-step x-build (LDS outputs) ----
        if (tid < 32) {                       // wave0: s_l softmax
            const float sv = 24.f*cbuf[0] - 2.f*U.p.slg[tid];
            float m = sv;
#pragma unroll
            for (int mk = 16; mk >= 1; mk >>= 1) m = fmaxf(m, __shfl_xor(m, mk));
            const float e = __expf(sv - m);
            float ss = e;
#pragma unroll
            for (int mk = 16; mk >= 1; mk >>= 1) ss += __shfl_xor(ss, mk);
            const float r = e * rcp_(ss);
            lasb[t*32 + tid] = r;
            if (t < T_ - 1) U.p.xv[tid] = r * liN;
        } else if (tid >= 64 && tid < 128) {  // wave1: s_g softmax, 4 s/lane
            const int lane = tid - 64;
            float vv0, vv1, vv2, vv3;
            {
                const float t0 = U.p.sgred[lane]     + U.p.sgred[256+lane]     + U.p.sgred[512+lane]     + U.p.sgred[768+lane];
                const float t1 = U.p.sgred[lane+64]  + U.p.sgred[256+lane+64]  + U.p.sgred[512+lane+64]  + U.p.sgred[768+lane+64];
                const float t2 = U.p.sgred[lane+128] + U.p.sgred[256+lane+128] + U.p.sgred[512+lane+128] + U.p.sgred[768+lane+128];
                const float t3 = U.p.sgred[lane+192] + U.p.sgred[256+lane+192] + U.p.sgred[512+lane+192] + U.p.sgred[768+lane+192];
                vv0 = (1.f-LAMDA_)*(24.f*cbuf[1] - 2.f*t0) + LAMDA_*dstf[lane];
                vv1 = (1.f-LAMDA_)*(24.f*cbuf[1] - 2.f*t1) + LAMDA_*dstf[lane+64];
                vv2 = (1.f-LAMDA_)*(24.f*cbuf[1] - 2.f*t2) + LAMDA_*dstf[lane+128];
                vv3 = (1.f-LAMDA_)*(24.f*cbuf[1] - 2.f*t3) + LAMDA_*dstf[lane+192];
            }
            float m = fmaxf(fmaxf(vv0, vv1), fmaxf(vv2, vv3));
#pragma unroll
            for (int mk = 32; mk >= 1; mk >>= 1) m = fmaxf(m, __shfl_xor(m, mk));
            const float e0 = __expf(vv0 - m), e1 = __expf(vv1 - m);
            const float e2 = __expf(vv2 - m), e3 = __expf(vv3 - m);
            float ss = (e0 + e1) + (e2 + e3);
#pragma unroll
            for (int mk = 32; mk >= 1; mk >>= 1) ss += __shfl_xor(ss, mk);
            const float inv = rcp_(ss);
            const float r0 = e0*inv, r1 = e1*inv, r2 = e2*inv, r3 = e3*inv;
            float* gb = gasb + t*256;
            gb[lane] = r0; gb[lane+64] = r1; gb[lane+128] = r2; gb[lane+192] = r3;
            if (t < T_ - 1) {
                U.p.xv[32+lane]     = r0 * giN0;
                U.p.xv[32+lane+64]  = r1 * giN1;
                U.p.xv[32+lane+128] = r2 * giN2;
                U.p.xv[32+lane+192] = r3 * giN3;
            }
        }
        __syncthreads();
    }

    // ---- final flush: LDS output buffers -> global, coalesced ----
    for (int k = tid; k < 6144; k += 1024) {
        const int tt = k >> 8, ii = k & 255;
        out[tt*16384 + b*256 + ii]           = outb[k];
        out[OFF_GAS + tt*16384 + b*256 + ii] = gasb[k];
    }
    if (tid < 768) out[OFF_LAS + (tid >> 5)*2048 + b*32 + (tid & 31)] = lasb[tid];
    if (tid < 256) out[OFF_CS + b*256 + tid] = csb[tid];
}

extern "C" void kernel_launch(void* const* d_in, const int* in_sizes, int n_in,
                              void* d_out, int out_size, void* d_ws, size_t ws_size,
                              hipStream_t stream)
{
    const float* li   = (const float*)d_in[0];
    const float* gi   = (const float*)d_in[1];
    const float* ls   = (const float*)d_in[2];
    const float* gs   = (const float*)d_in[3];
    const float* dist = (const float*)d_in[4];
    const float* la0  = (const float*)d_in[5];
    const float* ga0  = (const float*)d_in[6];
    const float* Wcl  = (const float*)d_in[7];
    const float* bcl  = (const float*)d_in[8];
    const float* Wll  = (const float*)d_in[9];
    const float* bll  = (const float*)d_in[10];
    const float* vl   = (const float*)d_in[11];
    const float* Wcg  = (const float*)d_in[12];
    const float* bcg  = (const float*)d_in[13];
    const float* Wlg  = (const float*)d_in[14];
    const float* blg  = (const float*)d_in[15];
    const float* vg   = (const float*)d_in[16];
    const float* Wih  = (const float*)d_in[17];
    const float* bih  = (const float*)d_in[18];
    const float* bhh  = (const float*)d_in[19];

    spat_kernel<<<64, 1024, 0, stream>>>(li, gi, ls, gs, dist, la0, ga0,
                                         Wcl, bcl, Wll, bll, vl,
                                         Wcg, bcg, Wlg, blg, vg,
                                         Wih, bih, bhh, (float*)d_out);
}